// Round 4
// baseline (3379.487 us; speedup 1.0000x reference)
//
#include <hip/hip_runtime.h>
#include <hip/hip_bf16.h>

#define BB 64
#define TT 64
#define FF 256
#define CC 64
#define GG 256   // 4*C
#define HP 264   // padded f-rows per batch: 4 zero + 256 + 4 zero
#define TF 32    // f-rows per block
#define GST 264  // gates LDS row stride (floats); 264%32=8 -> 2-way (free)

using frag_ab = __attribute__((ext_vector_type(8))) short;  // 8 bf16
using f32x4   = __attribute__((ext_vector_type(4))) float;

__device__ __forceinline__ float sigmoidf_(float x) {
    return 1.0f / (1.0f + __expf(-x));
}
__device__ __forceinline__ float tanhf_(float x) {
    const float e = __expf(2.0f * x);
    return 1.0f - 2.0f / (e + 1.0f);
}
__device__ __forceinline__ void split2(float v, short* hi, short* lo) {
    __hip_bfloat16 h = __float2bfloat16(v);
    __hip_bfloat16 l = __float2bfloat16(v - __bfloat162float(h));
    *hi = *reinterpret_cast<short*>(&h);
    *lo = *reinterpret_cast<short*>(&l);
}

// ---- prep: split Wh/Wx/h0 into hi/lo bf16; zero the halo pad rows of both h buffers
__global__ __launch_bounds__(256) void prep_kernel(
    const float* __restrict__ Wh, const float* __restrict__ Wx,
    const float* __restrict__ h0,
    short* __restrict__ WhTh, short* __restrict__ WhTl,
    short* __restrict__ WxTh, short* __restrict__ WxTl,
    short* __restrict__ hAh, short* __restrict__ hAl,
    short* __restrict__ hBh, short* __restrict__ hBl)
{
    const int n = blockIdx.x * 256 + threadIdx.x;
    if (n < BB * HP * CC) {
        const int c = n & 63;
        const int r = (n >> 6) % HP;
        const int b = n / (HP * CC);
        if (r < 4 || r >= 260) {
            hAh[n] = 0; hAl[n] = 0; hBh[n] = 0; hBl[n] = 0;
        } else {
            split2(h0[(b * FF + (r - 4)) * CC + c], &hAh[n], &hAl[n]);
        }
    }
    if (n < 9 * GG * CC) {
        const int cin = n & 63;
        const int g = (n >> 6) & 255;
        const int k = n >> 14;
        split2(Wh[(k * CC + cin) * GG + g], &WhTh[n], &WhTl[n]);
    }
    if (n < GG * 32) {
        const int kz = n & 31;
        const int g = n >> 5;
        split2(kz < 9 ? Wx[kz * GG + g] : 0.0f, &WxTh[n], &WxTl[n]);
    }
}

__global__ __launch_bounds__(512, 4) void convlstm_step(
    const float* __restrict__ z,
    const short* __restrict__ hinh, const short* __restrict__ hinl,  // padded (B,HP,C)
    const float* __restrict__ c_in,
    const short* __restrict__ WhTh, const short* __restrict__ WhTl,
    const short* __restrict__ WxTh, const short* __restrict__ WxTl,
    const float* __restrict__ bias,
    short* __restrict__ houth, short* __restrict__ houtl,            // padded
    float* __restrict__ c_out,
    float* __restrict__ out, int t)
{
    __shared__ __align__(16) char hbyh[40 * 128];   // h hi tile rows f0-4..f0+35, swizzled
    __shared__ __align__(16) char zbyh[32 * 64];    // z hi tile [32 f][32 kz]
    __shared__ __align__(16) char zbyl[32 * 64];    // z lo tile
    __shared__ __align__(16) float gbuf[TF * GST];  // gates fp32, 33.8 KB

    const int b = blockIdx.x;
    const int f0 = blockIdx.y * TF;
    const int tid = threadIdx.x;
    const int lane = tid & 63;
    const int w = tid >> 6;          // 0..7 : owns g-cols [w*32, w*32+32)

    // ---- stage h_hi tile (40 rows, always in-bounds thanks to padding)
    if (tid < 40 * 8) {
        const int row = tid >> 3, slot = tid & 7;
        const frag_ab v = *reinterpret_cast<const frag_ab*>(
            hinh + ((b * HP + f0 + row) * CC + slot * 8));
        *reinterpret_cast<frag_ab*>(&hbyh[row * 128 + ((slot ^ (row & 7)) << 4)]) = v;
    }
    // ---- stage z tile [fl][kz<9] hi+lo
    if (tid < 128) {
        const int row = tid >> 2, slot = tid & 3;
        const float* zr = z + ((long)b * TT + t) * FF;
        short vh[8], vl[8];
        #pragma unroll
        for (int j = 0; j < 8; ++j) {
            const int kz = slot * 8 + j;
            const int f = f0 + row - 4 + kz;
            const float val = (kz < 9 && f >= 0 && f < FF) ? zr[f] : 0.0f;
            split2(val, &vh[j], &vl[j]);
        }
        const int a = row * 64 + ((slot ^ (row & 3)) << 4);
        *reinterpret_cast<frag_ab*>(&zbyh[a]) = *reinterpret_cast<frag_ab*>(vh);
        *reinterpret_cast<frag_ab*>(&zbyl[a]) = *reinterpret_cast<frag_ab*>(vl);
    }
    __syncthreads();

    const int rA = lane & 15;
    const int sA = lane >> 4;
    const int gbase = w * 32;

    f32x4 acc[2][2];
    #pragma unroll
    for (int gtI = 0; gtI < 2; ++gtI) {
        const float bv = bias[gbase + gtI * 16 + rA];
        acc[0][gtI] = (f32x4){bv, bv, bv, bv};
        acc[1][gtI] = acc[0][gtI];
    }

    const short* hlo = hinl + (b * HP + f0) * CC;  // row r -> + r*CC

    // ---- main loop: 9 taps x 2 cin-halves; hi from LDS, lo direct from global
    for (int k = 0; k < 9; ++k) {
        #pragma unroll
        for (int kk = 0; kk < 2; ++kk) {
            const int co = kk * 32 + sA * 8;
            const int boff0 = (k * GG + gbase + rA) * CC + co;
            const frag_ab bh0 = *reinterpret_cast<const frag_ab*>(WhTh + boff0);
            const frag_ab bl0 = *reinterpret_cast<const frag_ab*>(WhTl + boff0);
            const frag_ab bh1 = *reinterpret_cast<const frag_ab*>(WhTh + boff0 + 16 * CC);
            const frag_ab bl1 = *reinterpret_cast<const frag_ab*>(WhTl + boff0 + 16 * CC);

            const int r0 = rA + k;
            const int r1 = r0 + 16;
            const int sl = kk * 4 + sA;
            const frag_ab ah0 = *reinterpret_cast<const frag_ab*>(
                &hbyh[r0 * 128 + ((sl ^ (r0 & 7)) << 4)]);
            const frag_ab ah1 = *reinterpret_cast<const frag_ab*>(
                &hbyh[r1 * 128 + ((sl ^ (r1 & 7)) << 4)]);
            const frag_ab al0 = *reinterpret_cast<const frag_ab*>(hlo + r0 * CC + co);
            const frag_ab al1 = *reinterpret_cast<const frag_ab*>(hlo + r1 * CC + co);

            acc[0][0] = __builtin_amdgcn_mfma_f32_16x16x32_bf16(ah0, bh0, acc[0][0], 0, 0, 0);
            acc[0][0] = __builtin_amdgcn_mfma_f32_16x16x32_bf16(ah0, bl0, acc[0][0], 0, 0, 0);
            acc[0][0] = __builtin_amdgcn_mfma_f32_16x16x32_bf16(al0, bh0, acc[0][0], 0, 0, 0);
            acc[0][1] = __builtin_amdgcn_mfma_f32_16x16x32_bf16(ah0, bh1, acc[0][1], 0, 0, 0);
            acc[0][1] = __builtin_amdgcn_mfma_f32_16x16x32_bf16(ah0, bl1, acc[0][1], 0, 0, 0);
            acc[0][1] = __builtin_amdgcn_mfma_f32_16x16x32_bf16(al0, bh1, acc[0][1], 0, 0, 0);
            acc[1][0] = __builtin_amdgcn_mfma_f32_16x16x32_bf16(ah1, bh0, acc[1][0], 0, 0, 0);
            acc[1][0] = __builtin_amdgcn_mfma_f32_16x16x32_bf16(ah1, bl0, acc[1][0], 0, 0, 0);
            acc[1][0] = __builtin_amdgcn_mfma_f32_16x16x32_bf16(al1, bh0, acc[1][0], 0, 0, 0);
            acc[1][1] = __builtin_amdgcn_mfma_f32_16x16x32_bf16(ah1, bh1, acc[1][1], 0, 0, 0);
            acc[1][1] = __builtin_amdgcn_mfma_f32_16x16x32_bf16(ah1, bl1, acc[1][1], 0, 0, 0);
            acc[1][1] = __builtin_amdgcn_mfma_f32_16x16x32_bf16(al1, bh1, acc[1][1], 0, 0, 0);
        }
    }
    // ---- z tap
    {
        const int boff0 = (gbase + rA) * 32 + sA * 8;
        const frag_ab bh0 = *reinterpret_cast<const frag_ab*>(WxTh + boff0);
        const frag_ab bl0 = *reinterpret_cast<const frag_ab*>(WxTl + boff0);
        const frag_ab bh1 = *reinterpret_cast<const frag_ab*>(WxTh + boff0 + 16 * 32);
        const frag_ab bl1 = *reinterpret_cast<const frag_ab*>(WxTl + boff0 + 16 * 32);
        const int r0 = rA, r1 = rA + 16;
        const int a0 = r0 * 64 + ((sA ^ (r0 & 3)) << 4);
        const int a1 = r1 * 64 + ((sA ^ (r1 & 3)) << 4);
        const frag_ab ah0 = *reinterpret_cast<const frag_ab*>(&zbyh[a0]);
        const frag_ab al0 = *reinterpret_cast<const frag_ab*>(&zbyl[a0]);
        const frag_ab ah1 = *reinterpret_cast<const frag_ab*>(&zbyh[a1]);
        const frag_ab al1 = *reinterpret_cast<const frag_ab*>(&zbyl[a1]);

        acc[0][0] = __builtin_amdgcn_mfma_f32_16x16x32_bf16(ah0, bh0, acc[0][0], 0, 0, 0);
        acc[0][0] = __builtin_amdgcn_mfma_f32_16x16x32_bf16(ah0, bl0, acc[0][0], 0, 0, 0);
        acc[0][0] = __builtin_amdgcn_mfma_f32_16x16x32_bf16(al0, bh0, acc[0][0], 0, 0, 0);
        acc[0][1] = __builtin_amdgcn_mfma_f32_16x16x32_bf16(ah0, bh1, acc[0][1], 0, 0, 0);
        acc[0][1] = __builtin_amdgcn_mfma_f32_16x16x32_bf16(ah0, bl1, acc[0][1], 0, 0, 0);
        acc[0][1] = __builtin_amdgcn_mfma_f32_16x16x32_bf16(al0, bh1, acc[0][1], 0, 0, 0);
        acc[1][0] = __builtin_amdgcn_mfma_f32_16x16x32_bf16(ah1, bh0, acc[1][0], 0, 0, 0);
        acc[1][0] = __builtin_amdgcn_mfma_f32_16x16x32_bf16(ah1, bl0, acc[1][0], 0, 0, 0);
        acc[1][0] = __builtin_amdgcn_mfma_f32_16x16x32_bf16(al1, bh0, acc[1][0], 0, 0, 0);
        acc[1][1] = __builtin_amdgcn_mfma_f32_16x16x32_bf16(ah1, bh1, acc[1][1], 0, 0, 0);
        acc[1][1] = __builtin_amdgcn_mfma_f32_16x16x32_bf16(ah1, bl1, acc[1][1], 0, 0, 0);
        acc[1][1] = __builtin_amdgcn_mfma_f32_16x16x32_bf16(al1, bh1, acc[1][1], 0, 0, 0);
    }

    // ---- scatter gates to LDS
    #pragma unroll
    for (int Mt = 0; Mt < 2; ++Mt)
        #pragma unroll
        for (int gtI = 0; gtI < 2; ++gtI) {
            const int g = gbase + gtI * 16 + rA;
            float* gp = &gbuf[(Mt * 16 + sA * 4) * GST + g];
            gp[0]       = acc[Mt][gtI][0];
            gp[GST]     = acc[Mt][gtI][1];
            gp[2 * GST] = acc[Mt][gtI][2];
            gp[3 * GST] = acc[Mt][gtI][3];
        }
    __syncthreads();

    // ---- LSTM cell update: thread -> (fl = tid>>4, 4 channels)
    const int fl = tid >> 4;
    const int ch0 = (tid & 15) * 4;
    const float* gr = &gbuf[fl * GST];
    const f32x4 gi = *reinterpret_cast<const f32x4*>(gr + ch0);
    const f32x4 gj = *reinterpret_cast<const f32x4*>(gr + 64 + ch0);
    const f32x4 gf = *reinterpret_cast<const f32x4*>(gr + 128 + ch0);
    const f32x4 go = *reinterpret_cast<const f32x4*>(gr + 192 + ch0);

    const int cix = (b * FF + f0 + fl) * CC + ch0;
    const float4 cold = *reinterpret_cast<const float4*>(&c_in[cix]);
    const float co_[4] = {cold.x, cold.y, cold.z, cold.w};

    float hsum = 0.0f;
    float cv[4];
    short hh[4], hl[4];
    #pragma unroll
    for (int j = 0; j < 4; ++j) {
        const float cnew = co_[j] * sigmoidf_(gf[j] + 1.0f) + sigmoidf_(gi[j]) * tanhf_(gj[j]);
        const float hnew = tanhf_(cnew) * sigmoidf_(go[j]);
        cv[j] = cnew;
        split2(hnew, &hh[j], &hl[j]);
        hsum += hnew;
    }
    *reinterpret_cast<float4*>(&c_out[cix]) = make_float4(cv[0], cv[1], cv[2], cv[3]);
    const int hix = (b * HP + 4 + f0 + fl) * CC + ch0;
    *reinterpret_cast<uint2*>(&houth[hix]) = *reinterpret_cast<uint2*>(hh);
    *reinterpret_cast<uint2*>(&houtl[hix]) = *reinterpret_cast<uint2*>(hl);

    hsum += __shfl_xor(hsum, 1);
    hsum += __shfl_xor(hsum, 2);
    hsum += __shfl_xor(hsum, 4);
    hsum += __shfl_xor(hsum, 8);
    if ((tid & 15) == 0)
        out[(long)b * (TT * FF) + t * FF + f0 + fl] = tanhf_(hsum * (1.0f / 64.0f));
}

extern "C" void kernel_launch(void* const* d_in, const int* in_sizes, int n_in,
                              void* d_out, int out_size, void* d_ws, size_t ws_size,
                              hipStream_t stream) {
    const float* z    = (const float*)d_in[0];
    const float* h0   = (const float*)d_in[1];
    const float* c0   = (const float*)d_in[2];
    const float* Wx   = (const float*)d_in[3];
    const float* Wh   = (const float*)d_in[4];
    const float* bias = (const float*)d_in[5];
    float* out = (float*)d_out;

    const int SEp = BB * HP * CC;   // 1,081,344 (padded h elems)
    const int SE  = BB * FF * CC;   // 1,048,576
    short* hAh = (short*)d_ws;
    short* hAl = hAh + SEp;
    short* hBh = hAl + SEp;
    short* hBl = hBh + SEp;
    float* cW  = (float*)(hBl + SEp);
    short* WhTh = (short*)(cW + SE);
    short* WhTl = WhTh + 9 * GG * CC;
    short* WxTh = WhTl + 9 * GG * CC;
    short* WxTl = WxTh + GG * 32;

    prep_kernel<<<(SEp + 255) / 256, 256, 0, stream>>>(Wh, Wx, h0, WhTh, WhTl,
                                                       WxTh, WxTl, hAh, hAl, hBh, hBl);

    dim3 grid(BB, FF / TF);  // 64 x 8 = 512 blocks
    for (int t = 0; t < TT; ++t) {
        const short* hih = (t & 1) ? hBh : hAh;
        const short* hil = (t & 1) ? hBl : hAl;
        short* hoh = (t & 1) ? hAh : hBh;
        short* hol = (t & 1) ? hAl : hBl;
        const float* cin = (t == 0) ? c0 : cW;
        convlstm_step<<<grid, 512, 0, stream>>>(z, hih, hil, cin,
                                                WhTh, WhTl, WxTh, WxTl, bias,
                                                hoh, hol, cW, out, t);
    }
}

// Round 5
// 1025.846 us; speedup vs baseline: 3.2943x; 3.2943x over previous
//
#include <hip/hip_runtime.h>
#include <hip/hip_bf16.h>

#define BB 64
#define TT 64
#define FF 256
#define CC 64
#define GG 256   // 4*C
#define HP 264   // padded f-rows per batch: 4 zero + 256 + 4 zero
#define GST 264  // gates LDS row stride (floats)

using frag_ab = __attribute__((ext_vector_type(8))) short;  // 8 bf16
using f32x4   = __attribute__((ext_vector_type(4))) float;

__device__ __forceinline__ float sigmoidf_(float x) {
    return 1.0f / (1.0f + __expf(-x));
}
__device__ __forceinline__ float tanhf_(float x) {
    const float e = __expf(2.0f * x);
    return 1.0f - 2.0f / (e + 1.0f);
}
__device__ __forceinline__ void split2(float v, short* hi, short* lo) {
    __hip_bfloat16 h = __float2bfloat16(v);
    __hip_bfloat16 l = __float2bfloat16(v - __bfloat162float(h));
    *hi = *reinterpret_cast<short*>(&h);
    *lo = *reinterpret_cast<short*>(&l);
}

// ---- prep: Wh -> packed [p=(k*2+kk)][g][cin32] hi/lo; Wx -> [g][32] hi/lo;
//      h0 -> padded (B,HP,C) hi/lo with zeroed halos in both ping-pong buffers
__global__ __launch_bounds__(256) void prep_kernel(
    const float* __restrict__ Wh, const float* __restrict__ Wx,
    const float* __restrict__ h0,
    short* __restrict__ WhPh, short* __restrict__ WhPl,
    short* __restrict__ WxTh, short* __restrict__ WxTl,
    short* __restrict__ hAh, short* __restrict__ hAl,
    short* __restrict__ hBh, short* __restrict__ hBl)
{
    const int n = blockIdx.x * 256 + threadIdx.x;
    if (n < BB * HP * CC) {
        const int c = n & 63;
        const int r = (n >> 6) % HP;
        const int b = n / (HP * CC);
        if (r < 4 || r >= 260) {
            hAh[n] = 0; hAl[n] = 0; hBh[n] = 0; hBl[n] = 0;
        } else {
            split2(h0[(b * FF + (r - 4)) * CC + c], &hAh[n], &hAl[n]);
        }
    }
    if (n < 9 * GG * CC) {
        // packed: n = (p*256 + g)*32 + c32
        const int c32 = n & 31;
        const int g = (n >> 5) & 255;
        const int p = n >> 13;
        const int k = p >> 1;
        const int cin = (p & 1) * 32 + c32;
        split2(Wh[(k * CC + cin) * GG + g], &WhPh[n], &WhPl[n]);
    }
    if (n < GG * 32) {
        const int kz = n & 31;
        const int g = n >> 5;
        split2(kz < 9 ? Wx[kz * GG + g] : 0.0f, &WxTh[n], &WxTl[n]);
    }
}

__global__ __launch_bounds__(512, 4) void convlstm_step(
    const float* __restrict__ z,
    const short* __restrict__ hinh, const short* __restrict__ hinl,  // padded (B,HP,C)
    const float* __restrict__ c_in,
    const short* __restrict__ WhPh, const short* __restrict__ WhPl,
    const short* __restrict__ WxTh, const short* __restrict__ WxTl,
    const float* __restrict__ bias,
    short* __restrict__ houth, short* __restrict__ houtl,            // padded
    float* __restrict__ c_out,
    float* __restrict__ out, int t)
{
    __shared__ __align__(16) char hbyh[72 * 128];   // h hi tile, swizzled
    __shared__ __align__(16) char hbyl[72 * 128];   // h lo tile
    __shared__ __align__(16) char zbyh[64 * 64];    // z hi tile [64 f][32 kz]
    __shared__ __align__(16) char zbyl[64 * 64];
    __shared__ __align__(16) float gbuf[32 * GST];  // gates fp32, two-pass (33.8 KB)

    const int b = blockIdx.x;
    const int f0 = blockIdx.y * 64;
    const int tid = threadIdx.x;
    const int lane = tid & 63;
    const int w = tid >> 6;          // 0..7 : owns g-cols [w*32, w*32+32)

    // ---- stage h tile rows f0..f0+71 (padded space; always in-bounds)
    for (int idx = tid; idx < 72 * 8; idx += 512) {
        const int row = idx >> 3, slot = idx & 7;
        const int off = (b * HP + f0 + row) * CC + slot * 8;
        const frag_ab vh = *reinterpret_cast<const frag_ab*>(hinh + off);
        const frag_ab vl = *reinterpret_cast<const frag_ab*>(hinl + off);
        const int a = row * 128 + ((slot ^ (row & 7)) << 4);
        *reinterpret_cast<frag_ab*>(&hbyh[a]) = vh;
        *reinterpret_cast<frag_ab*>(&hbyl[a]) = vl;
    }
    // ---- stage z tile [64 f][kz<9] hi+lo
    if (tid < 256) {
        const int row = tid >> 2, slot = tid & 3;
        const float* zr = z + ((long)b * TT + t) * FF;
        short vh[8], vl[8];
        #pragma unroll
        for (int j = 0; j < 8; ++j) {
            const int kz = slot * 8 + j;
            const int f = f0 + row - 4 + kz;
            const float val = (kz < 9 && f >= 0 && f < FF) ? zr[f] : 0.0f;
            split2(val, &vh[j], &vl[j]);
        }
        const int a = row * 64 + ((slot ^ (row & 3)) << 4);
        *reinterpret_cast<frag_ab*>(&zbyh[a]) = *reinterpret_cast<frag_ab*>(vh);
        *reinterpret_cast<frag_ab*>(&zbyl[a]) = *reinterpret_cast<frag_ab*>(vl);
    }
    __syncthreads();

    const int rA = lane & 15;
    const int sA = lane >> 4;
    const int gbase = w * 32;

    f32x4 acc[4][2];
    #pragma unroll
    for (int gtI = 0; gtI < 2; ++gtI) {
        const float bv = bias[gbase + gtI * 16 + rA];
        #pragma unroll
        for (int Mt = 0; Mt < 4; ++Mt) acc[Mt][gtI] = (f32x4){bv, bv, bv, bv};
    }

    // ---- B fragments: packed layout, contiguous 1KB per wave per frag
    const int bln = rA * 32 + sA * 8;   // per-lane elem offset within fragment
    frag_ab cb[4];
    {
        const int o0 = (0 * GG + gbase) * 32 + bln;
        cb[0] = *reinterpret_cast<const frag_ab*>(WhPh + o0);
        cb[1] = *reinterpret_cast<const frag_ab*>(WhPh + o0 + 16 * 32);
        cb[2] = *reinterpret_cast<const frag_ab*>(WhPl + o0);
        cb[3] = *reinterpret_cast<const frag_ab*>(WhPl + o0 + 16 * 32);
    }

    // ---- 18 Wh phases (k=p>>1, kk=p&1), B prefetched one phase ahead
    #pragma unroll
    for (int p = 0; p < 18; ++p) {
        frag_ab nb[4];
        if (p < 17) {
            const int o0 = ((p + 1) * GG + gbase) * 32 + bln;
            nb[0] = *reinterpret_cast<const frag_ab*>(WhPh + o0);
            nb[1] = *reinterpret_cast<const frag_ab*>(WhPh + o0 + 16 * 32);
            nb[2] = *reinterpret_cast<const frag_ab*>(WhPl + o0);
            nb[3] = *reinterpret_cast<const frag_ab*>(WhPl + o0 + 16 * 32);
        } else {
            const int o0 = gbase * 32 + bln;
            nb[0] = *reinterpret_cast<const frag_ab*>(WxTh + o0);
            nb[1] = *reinterpret_cast<const frag_ab*>(WxTh + o0 + 16 * 32);
            nb[2] = *reinterpret_cast<const frag_ab*>(WxTl + o0);
            nb[3] = *reinterpret_cast<const frag_ab*>(WxTl + o0 + 16 * 32);
        }
        const int k = p >> 1, kk = p & 1;
        const int sl = kk * 4 + sA;
        frag_ab ah[4], al[4];
        #pragma unroll
        for (int Mt = 0; Mt < 4; ++Mt) {
            const int r = Mt * 16 + rA + k;
            const int a = r * 128 + ((sl ^ (r & 7)) << 4);
            ah[Mt] = *reinterpret_cast<const frag_ab*>(&hbyh[a]);
            al[Mt] = *reinterpret_cast<const frag_ab*>(&hbyl[a]);
        }
        #pragma unroll
        for (int Mt = 0; Mt < 4; ++Mt) {
            acc[Mt][0] = __builtin_amdgcn_mfma_f32_16x16x32_bf16(ah[Mt], cb[0], acc[Mt][0], 0, 0, 0);
            acc[Mt][1] = __builtin_amdgcn_mfma_f32_16x16x32_bf16(ah[Mt], cb[1], acc[Mt][1], 0, 0, 0);
        }
        #pragma unroll
        for (int Mt = 0; Mt < 4; ++Mt) {
            acc[Mt][0] = __builtin_amdgcn_mfma_f32_16x16x32_bf16(ah[Mt], cb[2], acc[Mt][0], 0, 0, 0);
            acc[Mt][1] = __builtin_amdgcn_mfma_f32_16x16x32_bf16(ah[Mt], cb[3], acc[Mt][1], 0, 0, 0);
        }
        #pragma unroll
        for (int Mt = 0; Mt < 4; ++Mt) {
            acc[Mt][0] = __builtin_amdgcn_mfma_f32_16x16x32_bf16(al[Mt], cb[0], acc[Mt][0], 0, 0, 0);
            acc[Mt][1] = __builtin_amdgcn_mfma_f32_16x16x32_bf16(al[Mt], cb[1], acc[Mt][1], 0, 0, 0);
        }
        cb[0] = nb[0]; cb[1] = nb[1]; cb[2] = nb[2]; cb[3] = nb[3];
    }
    // ---- z tap (B = Wx frags already in cb)
    {
        frag_ab ah[4], al[4];
        #pragma unroll
        for (int Mt = 0; Mt < 4; ++Mt) {
            const int r = Mt * 16 + rA;
            const int a = r * 64 + ((sA ^ (r & 3)) << 4);
            ah[Mt] = *reinterpret_cast<const frag_ab*>(&zbyh[a]);
            al[Mt] = *reinterpret_cast<const frag_ab*>(&zbyl[a]);
        }
        #pragma unroll
        for (int Mt = 0; Mt < 4; ++Mt) {
            acc[Mt][0] = __builtin_amdgcn_mfma_f32_16x16x32_bf16(ah[Mt], cb[0], acc[Mt][0], 0, 0, 0);
            acc[Mt][1] = __builtin_amdgcn_mfma_f32_16x16x32_bf16(ah[Mt], cb[1], acc[Mt][1], 0, 0, 0);
            acc[Mt][0] = __builtin_amdgcn_mfma_f32_16x16x32_bf16(ah[Mt], cb[2], acc[Mt][0], 0, 0, 0);
            acc[Mt][1] = __builtin_amdgcn_mfma_f32_16x16x32_bf16(ah[Mt], cb[3], acc[Mt][1], 0, 0, 0);
            acc[Mt][0] = __builtin_amdgcn_mfma_f32_16x16x32_bf16(al[Mt], cb[0], acc[Mt][0], 0, 0, 0);
            acc[Mt][1] = __builtin_amdgcn_mfma_f32_16x16x32_bf16(al[Mt], cb[1], acc[Mt][1], 0, 0, 0);
        }
    }

    // ---- two-pass epilogue through 32-row gbuf
    #pragma unroll
    for (int pass = 0; pass < 2; ++pass) {
        if (pass) __syncthreads();   // pass-0 reads done before overwrite
        #pragma unroll
        for (int Mh = 0; Mh < 2; ++Mh) {
            const int Mt = pass * 2 + Mh;
            #pragma unroll
            for (int gtI = 0; gtI < 2; ++gtI) {
                const int g = gbase + gtI * 16 + rA;
                float* gp = &gbuf[(Mh * 16 + sA * 4) * GST + g];
                gp[0]       = acc[Mt][gtI][0];
                gp[GST]     = acc[Mt][gtI][1];
                gp[2 * GST] = acc[Mt][gtI][2];
                gp[3 * GST] = acc[Mt][gtI][3];
            }
        }
        __syncthreads();

        const int fl = tid >> 4;             // 0..31
        const int ch0 = (tid & 15) * 4;
        const int frow = pass * 32 + fl;
        const int f = f0 + frow;
        const float* gr = &gbuf[fl * GST];
        const f32x4 gi = *reinterpret_cast<const f32x4*>(gr + ch0);
        const f32x4 gj = *reinterpret_cast<const f32x4*>(gr + 64 + ch0);
        const f32x4 gf = *reinterpret_cast<const f32x4*>(gr + 128 + ch0);
        const f32x4 go = *reinterpret_cast<const f32x4*>(gr + 192 + ch0);

        const int cix = (b * FF + f) * CC + ch0;
        const float4 cold = *reinterpret_cast<const float4*>(&c_in[cix]);
        const float co_[4] = {cold.x, cold.y, cold.z, cold.w};

        float hsum = 0.0f;
        float cv[4];
        short hh[4], hl[4];
        #pragma unroll
        for (int j = 0; j < 4; ++j) {
            const float cnew = co_[j] * sigmoidf_(gf[j] + 1.0f) + sigmoidf_(gi[j]) * tanhf_(gj[j]);
            const float hnew = tanhf_(cnew) * sigmoidf_(go[j]);
            cv[j] = cnew;
            split2(hnew, &hh[j], &hl[j]);
            hsum += hnew;
        }
        *reinterpret_cast<float4*>(&c_out[cix]) = make_float4(cv[0], cv[1], cv[2], cv[3]);
        const int hix = (b * HP + 4 + f) * CC + ch0;
        *reinterpret_cast<uint2*>(&houth[hix]) = *reinterpret_cast<uint2*>(hh);
        *reinterpret_cast<uint2*>(&houtl[hix]) = *reinterpret_cast<uint2*>(hl);

        hsum += __shfl_xor(hsum, 1);
        hsum += __shfl_xor(hsum, 2);
        hsum += __shfl_xor(hsum, 4);
        hsum += __shfl_xor(hsum, 8);
        if ((tid & 15) == 0)
            out[(long)b * (TT * FF) + t * FF + f] = tanhf_(hsum * (1.0f / 64.0f));
    }
}

extern "C" void kernel_launch(void* const* d_in, const int* in_sizes, int n_in,
                              void* d_out, int out_size, void* d_ws, size_t ws_size,
                              hipStream_t stream) {
    const float* z    = (const float*)d_in[0];
    const float* h0   = (const float*)d_in[1];
    const float* c0   = (const float*)d_in[2];
    const float* Wx   = (const float*)d_in[3];
    const float* Wh   = (const float*)d_in[4];
    const float* bias = (const float*)d_in[5];
    float* out = (float*)d_out;

    const int SEp = BB * HP * CC;   // 1,081,344 (padded h elems)
    const int SE  = BB * FF * CC;   // 1,048,576
    short* hAh = (short*)d_ws;
    short* hAl = hAh + SEp;
    short* hBh = hAl + SEp;
    short* hBl = hBh + SEp;
    float* cW  = (float*)(hBl + SEp);
    short* WhPh = (short*)(cW + SE);
    short* WhPl = WhPh + 9 * GG * CC;
    short* WxTh = WhPl + 9 * GG * CC;
    short* WxTl = WxTh + GG * 32;

    prep_kernel<<<(SEp + 255) / 256, 256, 0, stream>>>(Wh, Wx, h0, WhPh, WhPl,
                                                       WxTh, WxTl, hAh, hAl, hBh, hBl);

    dim3 grid(BB, FF / 64);  // 64 x 4 = 256 blocks
    for (int t = 0; t < TT; ++t) {
        const short* hih = (t & 1) ? hBh : hAh;
        const short* hil = (t & 1) ? hBl : hAl;
        short* hoh = (t & 1) ? hAh : hBh;
        short* hol = (t & 1) ? hAl : hBl;
        const float* cin = (t == 0) ? c0 : cW;
        convlstm_step<<<grid, 512, 0, stream>>>(z, hih, hil, cin,
                                                WhPh, WhPl, WxTh, WxTl, bias,
                                                hoh, hol, cW, out, t);
    }
}